// Round 1
// baseline (1418.888 us; speedup 1.0000x reference)
//
#include <hip/hip_runtime.h>
#include <hip/hip_bf16.h>

#define ALPHA_ 0.2f
#define EPS_ 1e-12f

constexpr int BB = 16, KK = 16, DD = 256, NNEG = 16384;
constexpr int ITERS = 8;   // Newton-Schulz iterations (even => result lands in XA)

// ---- workspace layout (float offsets) ----
constexpr size_t OFF_XA    = 0;                    // 16*256*256
constexpr size_t OFF_XB    = 1048576;              // 16*256*256
constexpr size_t OFF_T     = 2097152;              // 16*256*256
constexpr size_t OFF_NT    = 1048576;              // 256*16384  (aliases XB+T, used after Newton)
constexpr size_t OFF_BOUND = 5242880;              // 16
constexpr size_t OFF_PAP   = 5242896;              // 256
constexpr size_t OFF_DPOS2 = 5243152;              // 256
constexpr size_t OFF_PAT   = 5243408;              // 16*256*16
constexpr size_t OFF_MINA  = 5308944;              // 256 (uint)
constexpr size_t OFF_MINV  = 5309200;              // 256 (uint)
// total = 5309456 floats = 21.2 MB

// ---------- spectral bound per batch: scale = 2/(1+B) ----------
__global__ __launch_bounds__(256) void kbound(const float* __restrict__ Sig, float* __restrict__ ws) {
    int b = blockIdx.x, t = threadIdx.x;
    const float* S = Sig + (size_t)b * DD * DD;
    __shared__ float v[DD];
    __shared__ float red[256];
    // Gershgorin: max column abs-sum (== row sum, symmetric)
    float cs = 0.f;
    for (int i = 0; i < DD; ++i) cs += fabsf(S[i * DD + t]);
    red[t] = cs; __syncthreads();
    for (int s = 128; s > 0; s >>= 1) { if (t < s) red[t] = fmaxf(red[t], red[t + s]); __syncthreads(); }
    float G = red[0]; __syncthreads();
    // power iteration (12 steps)
    v[t] = 1.f; __syncthreads();
    for (int it = 0; it < 12; ++it) {
        float w = 0.f;
        for (int i = 0; i < DD; ++i) w = fmaf(S[i * DD + t], v[i], w);
        red[t] = w * w; __syncthreads();
        for (int s = 128; s > 0; s >>= 1) { if (t < s) red[t] += red[t + s]; __syncthreads(); }
        float nrm = sqrtf(red[0]); __syncthreads();
        v[t] = w / nrm; __syncthreads();
    }
    float w2 = 0.f;
    for (int i = 0; i < DD; ++i) w2 = fmaf(S[i * DD + t], v[i], w2);
    red[t] = w2 * v[t]; __syncthreads();
    for (int s = 128; s > 0; s >>= 1) { if (t < s) red[t] += red[t + s]; __syncthreads(); }
    if (t == 0) {
        float lam = red[0];                       // Rayleigh quotient, v unit
        float Bb = fminf(G, 1.06f * lam + 0.05f); // Newton still converges even if B in [lam-1, lam]
        ws[OFF_BOUND + b] = 2.f / (1.f + Bb);
    }
}

// ---------- X0 = scale * I ----------
__global__ __launch_bounds__(256) void kinitx(float* __restrict__ ws) {
    int idx = blockIdx.x * 256 + threadIdx.x;     // < 16*65536
    int b = idx >> 16, r = (idx >> 8) & 255, c = idx & 255;
    float s = ws[OFF_BOUND + b];
    ws[OFF_XA + idx] = (r == c) ? s : 0.f;
}

// ---------- batched 256x256 SGEMM: C = A@B (mode 0) or C = 2I - A@B (mode 1) ----------
__global__ __launch_bounds__(256) void gemm256(const float* __restrict__ Ab, const float* __restrict__ Bmat,
                                               float* __restrict__ Cb, int mode) {
    int b = blockIdx.y;
    int ti = blockIdx.x >> 2, tj = blockIdx.x & 3;
    const float* Ap = Ab + (size_t)b * 65536;
    const float* Bp = Bmat + (size_t)b * 65536;
    float* Cp = Cb + (size_t)b * 65536;
    int i0 = ti * 64, j0 = tj * 64;
    int t = threadIdx.x, tx = t & 15, ty = t >> 4;
    __shared__ float AsT[64 * 68];   // [k][i]
    __shared__ float Bs[64 * 68];    // [k][j]
    float acc[4][4] = {};
    for (int k0 = 0; k0 < 256; k0 += 64) {
        __syncthreads();
        #pragma unroll
        for (int w = 0; w < 16; ++w) {
            int lin = w * 256 + t;
            int r = lin >> 6, c = lin & 63;
            AsT[c * 68 + r] = Ap[(size_t)(i0 + r) * 256 + k0 + c];
            Bs[r * 68 + c]  = Bp[(size_t)(k0 + r) * 256 + j0 + c];
        }
        __syncthreads();
        #pragma unroll 8
        for (int kk = 0; kk < 64; ++kk) {
            float4 a  = *reinterpret_cast<const float4*>(&AsT[kk * 68 + ty * 4]);
            float4 bv = *reinterpret_cast<const float4*>(&Bs[kk * 68 + tx * 4]);
            float av[4] = {a.x, a.y, a.z, a.w};
            float bw[4] = {bv.x, bv.y, bv.z, bv.w};
            #pragma unroll
            for (int ii = 0; ii < 4; ++ii)
                #pragma unroll
                for (int jj = 0; jj < 4; ++jj)
                    acc[ii][jj] = fmaf(av[ii], bw[jj], acc[ii][jj]);
        }
    }
    #pragma unroll
    for (int ii = 0; ii < 4; ++ii) {
        int ri = i0 + ty * 4 + ii;
        float4 o;
        float* op = &o.x;
        #pragma unroll
        for (int jj = 0; jj < 4; ++jj) {
            int cj = j0 + tx * 4 + jj;
            float val = acc[ii][jj];
            if (mode == 1) val = ((ri == cj) ? 2.f : 0.f) - val;
            op[jj] = val;
        }
        *reinterpret_cast<float4*>(&Cp[(size_t)ri * 256 + j0 + tx * 4]) = o;
    }
}

// ---------- transpose negatives: NT[e][n] = negs[n][e] ----------
__global__ __launch_bounds__(256) void ktransp(const float* __restrict__ negs, float* __restrict__ NT) {
    __shared__ float tl[64 * 65];
    int n0 = blockIdx.x * 64, e0 = blockIdx.y * 64;
    int t = threadIdx.x;
    int c = t & 63, rq = t >> 6;
    #pragma unroll
    for (int w = 0; w < 16; ++w) {
        int r = w * 4 + rq;
        tl[r * 65 + c] = negs[(size_t)(n0 + r) * DD + e0 + c];
    }
    __syncthreads();
    #pragma unroll
    for (int w = 0; w < 16; ++w) {
        int r = w * 4 + rq;
        NT[(size_t)(e0 + r) * NNEG + n0 + c] = tl[c * 65 + r];
    }
}

// ---------- per (b,k): PA row, pAp, dpos2 (clipped), PA^T ----------
__global__ __launch_bounds__(256) void k2(const float* __restrict__ Z1, const float* __restrict__ Z2,
                                          const int* __restrict__ match, const float* __restrict__ A_,
                                          float* __restrict__ ws) {
    int bk = blockIdx.x; int b = bk >> 4; int k = bk & 15; int t = threadIdx.x;
    const float* A = A_ + (size_t)b * 65536;
    __shared__ float z[DD], df[DD];
    __shared__ float red[256];
    int m = match[bk];
    float zv = Z1[(size_t)bk * DD + t];
    float qv = Z2[((size_t)b * KK + m) * DD + t];
    z[t] = zv; df[t] = zv - qv;
    __syncthreads();
    float pa = 0.f, da = 0.f;
    for (int e = 0; e < DD; ++e) {
        float Ae = A[(size_t)e * DD + t];       // coalesced across threads
        pa = fmaf(z[e], Ae, pa);
        da = fmaf(df[e], Ae, da);
    }
    ws[OFF_PAT + ((size_t)b * DD + t) * KK + k] = pa;   // PA^T[b][f][k]
    float dfv = df[t];
    red[t] = pa * zv; __syncthreads();
    for (int s = 128; s > 0; s >>= 1) { if (t < s) red[t] += red[t + s]; __syncthreads(); }
    float pAp = red[0]; __syncthreads();
    red[t] = da * dfv; __syncthreads();
    for (int s = 128; s > 0; s >>= 1) { if (t < s) red[t] += red[t + s]; __syncthreads(); }
    if (t == 0) {
        ws[OFF_PAP + bk]   = pAp;
        ws[OFF_DPOS2 + bk] = fmaxf(red[0], EPS_);
    }
}

__global__ void kinitmin(unsigned* __restrict__ a, unsigned* __restrict__ v) {
    int t = threadIdx.x;
    a[t] = 0x7f800000u; v[t] = 0x7f800000u;
}

// ---------- main kernel: nAn GEMM + pAn pass + semi-hard min, per (b, 128-neg tile) ----------
__global__ __launch_bounds__(256) void k3(const float* __restrict__ negs,
                                          const float* __restrict__ A_,
                                          const float* __restrict__ NT,
                                          const float* __restrict__ PAT,
                                          const float* __restrict__ pap,
                                          const float* __restrict__ dpos2,
                                          unsigned* __restrict__ mina,
                                          unsigned* __restrict__ minv) {
    int b = blockIdx.y;
    int n0 = blockIdx.x * 128;
    const float* A = A_ + (size_t)b * 65536;
    const float* PATb = PAT + (size_t)b * DD * KK;
    int t = threadIdx.x, tx = t & 15, ty = t >> 4;
    int r0 = ty * 8;

    __shared__ float NTc[32 * 128];    // e-chunk x 128 negatives   (also reused as 'red')
    __shared__ float Atb[32 * 128];    // e-chunk x 128 f-cols      (reused: pAn/nAn/min bufs)
    __shared__ float PATc[32 * 16];
    __shared__ float red[128 * 17];

    float rs[8] = {};
    float accp[8] = {};
    for (int pass = 0; pass < 2; ++pass) {
        int f0 = pass * 128;
        float acc[8][8] = {};
        for (int ch = 0; ch < 8; ++ch) {
            int e0 = ch * 32;
            __syncthreads();
            #pragma unroll
            for (int w = 0; w < 4; ++w) {                  // 1024 float4 slots
                int lin4 = w * 256 + t;
                int el = lin4 >> 5;
                int c4 = (lin4 & 31) * 4;
                *reinterpret_cast<float4*>(&NTc[el * 128 + c4]) =
                    *reinterpret_cast<const float4*>(&NT[(size_t)(e0 + el) * NNEG + n0 + c4]);
                *reinterpret_cast<float4*>(&Atb[el * 128 + c4]) =
                    *reinterpret_cast<const float4*>(&A[(size_t)(e0 + el) * DD + f0 + c4]);
            }
            if (pass == 1 && t < 128) {
                int el = t >> 2, k4 = (t & 3) * 4;
                *reinterpret_cast<float4*>(&PATc[el * 16 + k4]) =
                    *reinterpret_cast<const float4*>(&PATb[(size_t)(e0 + el) * KK + k4]);
            }
            __syncthreads();
            #pragma unroll 4
            for (int ee = 0; ee < 32; ++ee) {
                float4 a0 = *reinterpret_cast<const float4*>(&NTc[ee * 128 + r0]);
                float4 a1 = *reinterpret_cast<const float4*>(&NTc[ee * 128 + r0 + 4]);
                float4 b0 = *reinterpret_cast<const float4*>(&Atb[ee * 128 + tx * 4]);
                float4 b1 = *reinterpret_cast<const float4*>(&Atb[ee * 128 + 64 + tx * 4]);
                float av[8] = {a0.x,a0.y,a0.z,a0.w,a1.x,a1.y,a1.z,a1.w};
                float bw[8] = {b0.x,b0.y,b0.z,b0.w,b1.x,b1.y,b1.z,b1.w};
                #pragma unroll
                for (int ii = 0; ii < 8; ++ii)
                    #pragma unroll
                    for (int jj = 0; jj < 8; ++jj)
                        acc[ii][jj] = fmaf(av[ii], bw[jj], acc[ii][jj]);
                if (pass == 1) {
                    float bp = PATc[ee * 16 + tx];
                    #pragma unroll
                    for (int ii = 0; ii < 8; ++ii)
                        accp[ii] = fmaf(av[ii], bp, accp[ii]);
                }
            }
        }
        // fused rowsum: nAn partial = sum_f Y[n,f] * N[n,f] over this thread's 8 f-cols
        #pragma unroll
        for (int ii = 0; ii < 8; ++ii) {
            int n = n0 + r0 + ii;
            float4 g0 = *reinterpret_cast<const float4*>(&negs[(size_t)n * DD + f0 + tx * 4]);
            float4 g1 = *reinterpret_cast<const float4*>(&negs[(size_t)n * DD + f0 + 64 + tx * 4]);
            rs[ii] += acc[ii][0]*g0.x + acc[ii][1]*g0.y + acc[ii][2]*g0.z + acc[ii][3]*g0.w
                    + acc[ii][4]*g1.x + acc[ii][5]*g1.y + acc[ii][6]*g1.z + acc[ii][7]*g1.w;
        }
    }
    __syncthreads();  // everyone done with NTc/Atb as GEMM tiles

    float* pAn_lds = Atb;              // [128][17]
    float* nAn_lds = Atb + 2304;       // [128]
    float* mred_a  = Atb + 2560;       // [16][16]
    float* mred_v  = Atb + 2816;       // [16][16]

    #pragma unroll
    for (int ii = 0; ii < 8; ++ii) {
        red[(r0 + ii) * 17 + tx] = rs[ii];
        pAn_lds[(r0 + ii) * 17 + tx] = accp[ii];
    }
    __syncthreads();
    if (t < 128) {
        float s = 0.f;
        #pragma unroll
        for (int x = 0; x < 16; ++x) s += red[t * 17 + x];
        nAn_lds[t] = s;
    }
    __syncthreads();
    // d2 + semi-hard mins: thread (ty,tx): k = tx, negatives r0..r0+7
    float pApk = pap[b * 16 + tx];
    float dp2  = dpos2[b * 16 + tx];
    float mn_a = __int_as_float(0x7f800000);
    float mn_v = mn_a;
    #pragma unroll
    for (int ii = 0; ii < 8; ++ii) {
        int n = r0 + ii;
        float d2v = pApk - 2.f * pAn_lds[n * 17 + tx] + nAn_lds[n];
        float c = fmaxf(d2v, EPS_);
        mn_a = fminf(mn_a, c);
        if (c > dp2) mn_v = fminf(mn_v, c);
    }
    mred_a[ty * 16 + tx] = mn_a;
    mred_v[ty * 16 + tx] = mn_v;
    __syncthreads();
    if (ty == 0) {
        float ra = mred_a[tx], rv = mred_v[tx];
        #pragma unroll
        for (int y = 1; y < 16; ++y) {
            ra = fminf(ra, mred_a[y * 16 + tx]);
            rv = fminf(rv, mred_v[y * 16 + tx]);
        }
        atomicMin(&mina[b * 16 + tx], __float_as_uint(ra));
        atomicMin(&minv[b * 16 + tx], __float_as_uint(rv));
    }
}

// ---------- final loss ----------
__global__ __launch_bounds__(256) void k5(const float* __restrict__ dpos2,
                                          const unsigned* __restrict__ mina,
                                          const unsigned* __restrict__ minv,
                                          float* __restrict__ out) {
    int t = threadIdx.x;
    __shared__ float red[256];
    float dp = sqrtf(dpos2[t]);
    unsigned mv = minv[t], ma = mina[t];
    unsigned sel = (mv < 0x7f800000u) ? mv : ma;   // semi-hard if any valid, else global min
    float dn = sqrtf(__uint_as_float(sel));
    red[t] = fmaxf(dp - dn + ALPHA_, 0.f);
    __syncthreads();
    for (int s = 128; s > 0; s >>= 1) { if (t < s) red[t] += red[t + s]; __syncthreads(); }
    if (t == 0) out[0] = red[0] * (1.f / 256.f);
}

extern "C" void kernel_launch(void* const* d_in, const int* in_sizes, int n_in,
                              void* d_out, int out_size, void* d_ws, size_t ws_size,
                              hipStream_t stream) {
    (void)in_sizes; (void)n_in; (void)out_size; (void)ws_size;
    const float* Z1   = (const float*)d_in[0];
    const float* Z2   = (const float*)d_in[1];
    const int*   mat  = (const int*)d_in[2];
    const float* negs = (const float*)d_in[3];
    const float* Sig  = (const float*)d_in[4];
    float* ws = (float*)d_ws;
    float* XA = ws + OFF_XA;
    float* XB = ws + OFF_XB;
    float* Tm = ws + OFF_T;
    float* NT = ws + OFF_NT;
    unsigned* mina = (unsigned*)(ws + OFF_MINA);
    unsigned* minv = (unsigned*)(ws + OFF_MINV);
    float* out = (float*)d_out;

    kbound<<<BB, 256, 0, stream>>>(Sig, ws);
    kinitx<<<4096, 256, 0, stream>>>(ws);
    float* pa = XA; float* pb = XB;
    for (int it = 0; it < ITERS; ++it) {
        gemm256<<<dim3(16, BB), 256, 0, stream>>>(Sig, pa, Tm, 1);   // T = 2I - Sigma @ X
        gemm256<<<dim3(16, BB), 256, 0, stream>>>(pa, Tm, pb, 0);    // X' = X @ T
        float* tswap = pa; pa = pb; pb = tswap;
    }
    // ITERS even => pa == XA; XB/T now dead, safe to overlay NT
    ktransp<<<dim3(NNEG / 64, DD / 64), 256, 0, stream>>>(negs, NT);
    k2<<<BB * KK, 256, 0, stream>>>(Z1, Z2, mat, pa, ws);
    kinitmin<<<1, 256, 0, stream>>>(mina, minv);
    k3<<<dim3(NNEG / 128, BB), 256, 0, stream>>>(negs, pa, NT, ws + OFF_PAT,
                                                 ws + OFF_PAP, ws + OFF_DPOS2, mina, minv);
    k5<<<1, 256, 0, stream>>>(ws + OFF_DPOS2, mina, minv, out);
}

// Round 2
// 508.386 us; speedup vs baseline: 2.7910x; 2.7910x over previous
//
#include <hip/hip_runtime.h>
#include <hip/hip_bf16.h>

#define ALPHA_ 0.2f
#define EPS_ 1e-12f

typedef short short8 __attribute__((ext_vector_type(8)));
typedef float f32x4 __attribute__((ext_vector_type(4)));

constexpr int BB = 16, KK = 16, DD = 256, NNEG = 16384;
constexpr int ITERS = 8;   // Newton-Schulz iterations (even => final lands in XA)

// ---- workspace layout (float offsets) ---- total 5,309,456 floats = 21.2 MB (same as round 1)
constexpr size_t OFF_XA_F  = 0;         // 1048576 f32: final A (fp32, for k2)
constexpr size_t OFF_XA_H  = 1048576;   // 1048576 ushorts (bf16 hi)
constexpr size_t OFF_XA_L  = 1572864;
constexpr size_t OFF_XB_H  = 2097152;
constexpr size_t OFF_XB_L  = 2621440;
constexpr size_t OFF_T_H   = 3145728;
constexpr size_t OFF_T_L   = 3670016;
constexpr size_t OFF_S_H   = 4194304;
constexpr size_t OFF_S_L   = 4718592;
constexpr size_t OFF_PA_H  = 5242880;   // 16*16*256 ushorts
constexpr size_t OFF_PA_L  = 5275648;
constexpr size_t OFF_BOUND = 5308416;
constexpr size_t OFF_PAP   = 5308432;
constexpr size_t OFF_DPOS2 = 5308688;
constexpr size_t OFF_MINA  = 5308944;
constexpr size_t OFF_MINV  = 5309200;

// ---------- bf16 split helpers (RNE) ----------
__device__ inline unsigned short bf_hi(float x) {
    unsigned u = __float_as_uint(x);
    return (unsigned short)((u + 0x7fffu + ((u >> 16) & 1u)) >> 16);
}
__device__ inline float bf_tof(unsigned short h) { return __uint_as_float(((unsigned)h) << 16); }
__device__ inline void split2(float x, unsigned short& h, unsigned short& l) {
    h = bf_hi(x); l = bf_hi(x - bf_tof(h));
}

// ---------- spectral bound per batch: scale = 2/(1+B) ----------
__global__ __launch_bounds__(256) void kbound(const float* __restrict__ Sig, float* __restrict__ ws) {
    int b = blockIdx.x, t = threadIdx.x;
    const float* S = Sig + (size_t)b * DD * DD;
    __shared__ float v[DD];
    __shared__ float red[256];
    float cs = 0.f;
    for (int i = 0; i < DD; ++i) cs += fabsf(S[i * DD + t]);
    red[t] = cs; __syncthreads();
    for (int s = 128; s > 0; s >>= 1) { if (t < s) red[t] = fmaxf(red[t], red[t + s]); __syncthreads(); }
    float G = red[0]; __syncthreads();
    v[t] = 1.f; __syncthreads();
    for (int it = 0; it < 12; ++it) {
        float w = 0.f;
        for (int i = 0; i < DD; ++i) w = fmaf(S[i * DD + t], v[i], w);
        red[t] = w * w; __syncthreads();
        for (int s = 128; s > 0; s >>= 1) { if (t < s) red[t] += red[t + s]; __syncthreads(); }
        float nrm = sqrtf(red[0]); __syncthreads();
        v[t] = w / nrm; __syncthreads();
    }
    float w2 = 0.f;
    for (int i = 0; i < DD; ++i) w2 = fmaf(S[i * DD + t], v[i], w2);
    red[t] = w2 * v[t]; __syncthreads();
    for (int s = 128; s > 0; s >>= 1) { if (t < s) red[t] += red[t + s]; __syncthreads(); }
    if (t == 0) {
        float lam = red[0];
        float Bb = fminf(G, 1.06f * lam + 0.05f);
        ws[OFF_BOUND + b] = 2.f / (1.f + Bb);
    }
}

// ---------- generic fp32 -> bf16 hi/lo split ----------
__global__ __launch_bounds__(256) void ksplit(const float* __restrict__ in,
                                              unsigned short* __restrict__ h,
                                              unsigned short* __restrict__ l, int n) {
    int i = blockIdx.x * 256 + threadIdx.x;
    if (i < n) { unsigned short hh, ll; split2(in[i], hh, ll); h[i] = hh; l[i] = ll; }
}

// ---------- X0 = scale * I (split) ----------
__global__ __launch_bounds__(256) void kinitx(float* __restrict__ ws) {
    int idx = blockIdx.x * 256 + threadIdx.x;     // < 16*65536
    int b = idx >> 16, r = (idx >> 8) & 255, c = idx & 255;
    float s = ws[OFF_BOUND + b];
    float v = (r == c) ? s : 0.f;
    unsigned short h, l; split2(v, h, l);
    ((unsigned short*)(ws + OFF_XA_H))[idx] = h;
    ((unsigned short*)(ws + OFF_XA_L))[idx] = l;
}

// ---------- batched 256x256 MFMA split GEMM (operands symmetric: B-frags read rows) ----------
// mode2i: C = 2I - A@B, else C = A@B. Writes split C (+ optional fp32).
__global__ __launch_bounds__(256) void gemm_mfma(const unsigned short* __restrict__ Ah,
                                                 const unsigned short* __restrict__ Al,
                                                 const unsigned short* __restrict__ Bh,
                                                 const unsigned short* __restrict__ Bl,
                                                 unsigned short* __restrict__ Ch,
                                                 unsigned short* __restrict__ Cl,
                                                 float* __restrict__ Cf, int mode2i) {
    int b = blockIdx.y;
    int i0 = (blockIdx.x & 3) * 64, j0 = (blockIdx.x >> 2) * 64;
    size_t base = (size_t)b * 65536;
    int t = threadIdx.x, lane = t & 63, wid = t >> 6;
    int wm = wid & 1, wf = wid >> 1;
    int l15 = lane & 15, lg = lane >> 4;
    f32x4 acc[2][2] = {};
    int arow0 = i0 + wm * 32 + l15;
    int bcol0 = j0 + wf * 32 + l15;
    for (int e0 = 0; e0 < 256; e0 += 32) {
        int eoff = e0 + 8 * lg;
        short8 a_h[2], a_l[2], b_h[2], b_l[2];
        #pragma unroll
        for (int m = 0; m < 2; ++m) {
            size_t off = base + (size_t)(arow0 + m * 16) * 256 + eoff;
            a_h[m] = *reinterpret_cast<const short8*>(Ah + off);
            a_l[m] = *reinterpret_cast<const short8*>(Al + off);
        }
        #pragma unroll
        for (int n = 0; n < 2; ++n) {
            size_t off = base + (size_t)(bcol0 + n * 16) * 256 + eoff;  // symmetric: row == col
            b_h[n] = *reinterpret_cast<const short8*>(Bh + off);
            b_l[n] = *reinterpret_cast<const short8*>(Bl + off);
        }
        #pragma unroll
        for (int m = 0; m < 2; ++m)
            #pragma unroll
            for (int n = 0; n < 2; ++n) {
                acc[m][n] = __builtin_amdgcn_mfma_f32_16x16x32_bf16(a_h[m], b_h[n], acc[m][n], 0, 0, 0);
                acc[m][n] = __builtin_amdgcn_mfma_f32_16x16x32_bf16(a_h[m], b_l[n], acc[m][n], 0, 0, 0);
                acc[m][n] = __builtin_amdgcn_mfma_f32_16x16x32_bf16(a_l[m], b_h[n], acc[m][n], 0, 0, 0);
            }
    }
    #pragma unroll
    for (int m = 0; m < 2; ++m)
        #pragma unroll
        for (int n = 0; n < 2; ++n)
            #pragma unroll
            for (int r = 0; r < 4; ++r) {
                int row = i0 + wm * 32 + m * 16 + 4 * lg + r;   // C: col=lane&15, row=(lane>>4)*4+r
                int col = j0 + wf * 32 + n * 16 + l15;
                float v = acc[m][n][r];
                if (mode2i) v = ((row == col) ? 2.f : 0.f) - v;
                unsigned short h, l; split2(v, h, l);
                size_t off = base + (size_t)row * 256 + col;
                Ch[off] = h; Cl[off] = l;
                if (Cf) Cf[off] = v;
            }
}

// ---------- per (b,k): PA row (split), pAp, dpos2 ----------
__global__ __launch_bounds__(256) void k2(const float* __restrict__ Z1, const float* __restrict__ Z2,
                                          const int* __restrict__ match, const float* __restrict__ A_,
                                          float* __restrict__ ws) {
    int bk = blockIdx.x; int b = bk >> 4; int t = threadIdx.x;
    const float* A = A_ + (size_t)b * 65536;
    __shared__ float z[DD], df[DD];
    __shared__ float red[256];
    int m = match[bk];
    float zv = Z1[(size_t)bk * DD + t];
    float qv = Z2[((size_t)b * KK + m) * DD + t];
    z[t] = zv; df[t] = zv - qv;
    __syncthreads();
    float pa = 0.f, da = 0.f;
    for (int e = 0; e < DD; ++e) {
        float Ae = A[(size_t)e * DD + t];
        pa = fmaf(z[e], Ae, pa);
        da = fmaf(df[e], Ae, da);
    }
    unsigned short ph, pl; split2(pa, ph, pl);
    ((unsigned short*)(ws + OFF_PA_H))[(size_t)bk * 256 + t] = ph;   // PA[b][k][e]
    ((unsigned short*)(ws + OFF_PA_L))[(size_t)bk * 256 + t] = pl;
    float dfv = df[t];
    red[t] = pa * zv; __syncthreads();
    for (int s = 128; s > 0; s >>= 1) { if (t < s) red[t] += red[t + s]; __syncthreads(); }
    float pAp = red[0]; __syncthreads();
    red[t] = da * dfv; __syncthreads();
    for (int s = 128; s > 0; s >>= 1) { if (t < s) red[t] += red[t + s]; __syncthreads(); }
    if (t == 0) {
        ws[OFF_PAP + bk]   = pAp;
        ws[OFF_DPOS2 + bk] = fmaxf(red[0], EPS_);
    }
}

__global__ void kinitmin(unsigned* __restrict__ a, unsigned* __restrict__ v) {
    int t = threadIdx.x;
    a[t] = 0x7f800000u; v[t] = 0x7f800000u;
}

// ---------- main kernel: MFMA split GEMM  N @ [A | PA^T]  + fused nAn rowsum + semi-hard mins ----------
// Block: 256 thr = 4 waves (wm x wf = 2x2). n-tile 128, f-range 272 (256 A-cols + 16 PA).
__global__ __launch_bounds__(256, 2) void k3(const float* __restrict__ negs,
                                             const unsigned short* __restrict__ Ahi,
                                             const unsigned short* __restrict__ Alo,
                                             const unsigned short* __restrict__ PAh,
                                             const unsigned short* __restrict__ PAl,
                                             const float* __restrict__ pap,
                                             const float* __restrict__ dpos2,
                                             unsigned* __restrict__ mina,
                                             unsigned* __restrict__ minv) {
    __shared__ float smem[10880];                      // 43.5 KB
    unsigned short* Bh = (unsigned short*)smem;        // [272][40] bf16-hi, pad 40 (16B-aligned, 2-way banks)
    unsigned short* Bl = Bh + 272 * 40;

    int b = blockIdx.y;
    int n0 = blockIdx.x * 128;
    int t = threadIdx.x, lane = t & 63, wid = t >> 6;
    int wm = wid & 1, wf = wid >> 1;
    int l15 = lane & 15, lg = lane >> 4;
    const unsigned short* Ab = Ahi + (size_t)b * 65536;
    const unsigned short* Al_ = Alo + (size_t)b * 65536;
    const unsigned short* Ph = PAh + (size_t)b * 16 * 256;
    const unsigned short* Pl = PAl + (size_t)b * 16 * 256;

    f32x4 acc[4][9] = {};
    for (int e0 = 0; e0 < 256; e0 += 32) {
        __syncthreads();
        {   // stage B^T chunk: rows 0..255 = A rows (symmetric!), rows 256..271 = PA rows
            const unsigned short* sh = Ab + (size_t)t * 256 + e0;
            const unsigned short* sl = Al_ + (size_t)t * 256 + e0;
            #pragma unroll
            for (int j = 0; j < 4; ++j) {
                *reinterpret_cast<short8*>(&Bh[t * 40 + j * 8]) = *reinterpret_cast<const short8*>(sh + j * 8);
                *reinterpret_cast<short8*>(&Bl[t * 40 + j * 8]) = *reinterpret_cast<const short8*>(sl + j * 8);
            }
            if (t < 16) {
                int r2 = 256 + t;
                const unsigned short* ph = Ph + (size_t)t * 256 + e0;
                const unsigned short* pl = Pl + (size_t)t * 256 + e0;
                #pragma unroll
                for (int j = 0; j < 4; ++j) {
                    *reinterpret_cast<short8*>(&Bh[r2 * 40 + j * 8]) = *reinterpret_cast<const short8*>(ph + j * 8);
                    *reinterpret_cast<short8*>(&Bl[r2 * 40 + j * 8]) = *reinterpret_cast<const short8*>(pl + j * 8);
                }
            }
        }
        __syncthreads();
        // a-frags: negatives fp32 -> split on the fly
        short8 ah[4], al[4];
        #pragma unroll
        for (int m = 0; m < 4; ++m) {
            int n = n0 + wm * 64 + m * 16 + l15;
            const float* src = negs + (size_t)n * 256 + e0 + 8 * lg;
            f32x4 v0 = *reinterpret_cast<const f32x4*>(src);
            f32x4 v1 = *reinterpret_cast<const f32x4*>(src + 4);
            #pragma unroll
            for (int j = 0; j < 4; ++j) {
                unsigned short h, l;
                split2(v0[j], h, l); ah[m][j] = (short)h;     al[m][j] = (short)l;
                split2(v1[j], h, l); ah[m][4 + j] = (short)h; al[m][4 + j] = (short)l;
            }
        }
        #pragma unroll
        for (int ff = 0; ff < 9; ++ff) {
            if (ff < 8 || wf == 0) {     // wf1's ff=8 would be f>=272: skip
                int frow = wf * 144 + ff * 16 + l15;
                short8 bh = *reinterpret_cast<const short8*>(&Bh[frow * 40 + 8 * lg]);
                short8 bl = *reinterpret_cast<const short8*>(&Bl[frow * 40 + 8 * lg]);
                #pragma unroll
                for (int m = 0; m < 4; ++m) {
                    acc[m][ff] = __builtin_amdgcn_mfma_f32_16x16x32_bf16(ah[m], bh, acc[m][ff], 0, 0, 0);
                    acc[m][ff] = __builtin_amdgcn_mfma_f32_16x16x32_bf16(ah[m], bl, acc[m][ff], 0, 0, 0);
                    acc[m][ff] = __builtin_amdgcn_mfma_f32_16x16x32_bf16(al[m], bh, acc[m][ff], 0, 0, 0);
                }
            }
        }
    }
    __syncthreads();
    // ---- epilogue: nAn = rowsum(Y .* N) over f<256; pAn from PA frag (wf1, ff=7) ----
    float* pAn_l = smem;            // [128][17]
    float* nAnp  = smem + 2176;     // [2][128][17]
    float* nAn_l = smem + 6528;     // [128]
    float* reda  = smem + 6656;     // [256]
    float* redv  = smem + 6912;     // [256]

    #pragma unroll
    for (int m = 0; m < 4; ++m) {
        #pragma unroll
        for (int r = 0; r < 4; ++r) {
            int nl = wm * 64 + m * 16 + 4 * lg + r;     // C: row=(lane>>4)*4+r
            int n  = n0 + nl;
            float s = 0.f;
            #pragma unroll
            for (int ff = 0; ff < 9; ++ff) {
                int fb = wf * 144 + ff * 16;
                if (fb < 256) {                          // excludes PA frag & beyond
                    float w = negs[(size_t)n * 256 + fb + l15];
                    s = fmaf(acc[m][ff][r], w, s);
                }
            }
            nAnp[(wf * 128 + nl) * 17 + l15] = s;
            if (wf == 1) pAn_l[nl * 17 + l15] = acc[m][7][r];   // f = 256 + (lane&15) => k
        }
    }
    __syncthreads();
    if (t < 128) {
        float s = 0.f;
        #pragma unroll
        for (int x = 0; x < 16; ++x) s += nAnp[t * 17 + x] + nAnp[(128 + t) * 17 + x];
        nAn_l[t] = s;
    }
    __syncthreads();
    int tx = t & 15, ty = t >> 4;
    float pApk = pap[b * 16 + tx];
    float dp2  = dpos2[b * 16 + tx];
    float mn_a = __uint_as_float(0x7f800000u), mn_v = mn_a;
    #pragma unroll
    for (int ii = 0; ii < 8; ++ii) {
        int n = ty * 8 + ii;
        float d2v = pApk - 2.f * pAn_l[n * 17 + tx] + nAn_l[n];
        float c = fmaxf(d2v, EPS_);
        mn_a = fminf(mn_a, c);
        if (c > dp2) mn_v = fminf(mn_v, c);
    }
    reda[ty * 16 + tx] = mn_a; redv[ty * 16 + tx] = mn_v;
    __syncthreads();
    if (ty == 0) {
        float ra = reda[tx], rv = redv[tx];
        #pragma unroll
        for (int y = 1; y < 16; ++y) {
            ra = fminf(ra, reda[y * 16 + tx]);
            rv = fminf(rv, redv[y * 16 + tx]);
        }
        atomicMin(&mina[b * 16 + tx], __float_as_uint(ra));
        atomicMin(&minv[b * 16 + tx], __float_as_uint(rv));
    }
}

// ---------- final loss ----------
__global__ __launch_bounds__(256) void k5(const float* __restrict__ dpos2,
                                          const unsigned* __restrict__ mina,
                                          const unsigned* __restrict__ minv,
                                          float* __restrict__ out) {
    int t = threadIdx.x;
    __shared__ float red[256];
    float dp = sqrtf(dpos2[t]);
    unsigned mv = minv[t], ma = mina[t];
    unsigned sel = (mv < 0x7f800000u) ? mv : ma;
    float dn = sqrtf(__uint_as_float(sel));
    red[t] = fmaxf(dp - dn + ALPHA_, 0.f);
    __syncthreads();
    for (int s = 128; s > 0; s >>= 1) { if (t < s) red[t] += red[t + s]; __syncthreads(); }
    if (t == 0) out[0] = red[0] * (1.f / 256.f);
}

extern "C" void kernel_launch(void* const* d_in, const int* in_sizes, int n_in,
                              void* d_out, int out_size, void* d_ws, size_t ws_size,
                              hipStream_t stream) {
    (void)in_sizes; (void)n_in; (void)out_size; (void)ws_size;
    const float* Z1   = (const float*)d_in[0];
    const float* Z2   = (const float*)d_in[1];
    const int*   mat  = (const int*)d_in[2];
    const float* negs = (const float*)d_in[3];
    const float* Sig  = (const float*)d_in[4];
    float* ws = (float*)d_ws;
    unsigned short* S_H  = (unsigned short*)(ws + OFF_S_H);
    unsigned short* S_L  = (unsigned short*)(ws + OFF_S_L);
    unsigned short* XA_H = (unsigned short*)(ws + OFF_XA_H);
    unsigned short* XA_L = (unsigned short*)(ws + OFF_XA_L);
    unsigned short* XB_H = (unsigned short*)(ws + OFF_XB_H);
    unsigned short* XB_L = (unsigned short*)(ws + OFF_XB_L);
    unsigned short* T_H  = (unsigned short*)(ws + OFF_T_H);
    unsigned short* T_L  = (unsigned short*)(ws + OFF_T_L);
    unsigned short* PA_H = (unsigned short*)(ws + OFF_PA_H);
    unsigned short* PA_L = (unsigned short*)(ws + OFF_PA_L);
    unsigned* mina = (unsigned*)(ws + OFF_MINA);
    unsigned* minv = (unsigned*)(ws + OFF_MINV);
    float* out = (float*)d_out;

    kbound<<<BB, 256, 0, stream>>>(Sig, ws);
    ksplit<<<4096, 256, 0, stream>>>(Sig, S_H, S_L, BB * DD * DD);
    kinitx<<<4096, 256, 0, stream>>>(ws);

    unsigned short* pah = XA_H; unsigned short* pal = XA_L;
    unsigned short* pbh = XB_H; unsigned short* pbl = XB_L;
    for (int it = 0; it < ITERS; ++it) {
        // T = 2I - S @ X
        gemm_mfma<<<dim3(16, BB), 256, 0, stream>>>(S_H, S_L, pah, pal, T_H, T_L, nullptr, 1);
        // X' = X @ T   (write fp32 only on last iteration)
        float* cf = (it == ITERS - 1) ? (ws + OFF_XA_F) : nullptr;
        gemm_mfma<<<dim3(16, BB), 256, 0, stream>>>(pah, pal, T_H, T_L, pbh, pbl, cf, 0);
        unsigned short* th = pah; pah = pbh; pbh = th;
        unsigned short* tl = pal; pal = pbl; pbl = tl;
    }
    // after 8 iterations the final split inverse lives in XA_H/XA_L, fp32 in XA_F

    k2<<<BB * KK, 256, 0, stream>>>(Z1, Z2, mat, ws + OFF_XA_F, ws);
    kinitmin<<<1, 256, 0, stream>>>(mina, minv);
    k3<<<dim3(NNEG / 128, BB), 256, 0, stream>>>(negs, XA_H, XA_L, PA_H, PA_L,
                                                 ws + OFF_PAP, ws + OFF_DPOS2, mina, minv);
    k5<<<1, 256, 0, stream>>>(ws + OFF_DPOS2, mina, minv, out);
}